// Round 10
// baseline (139.296 us; speedup 1.0000x reference)
//
#include <hip/hip_runtime.h>
#include <hip/hip_fp16.h>

// out[n,c] = sum_{e: dst[e]==n} ( sum_k x[src[e],k]*W3[k]*x[dst[e],k] ) * x[src[e],c] * W2[c]
// B=1, N=100000, E=1600000, C=128.
//
// Pipeline (4 kernels + 1 tiny memset, no global atomic-returns in hot paths):
//   k_pack_hist : fused; x fp32->fp16 pack blocks + per-block coarse-bin
//                 histogram blocks (bin = dst>>5)
//   k_pscan     : single-pass exclusive scan of bin-major (bin,block) counts
//                 with decoupled lookback (replaces pscan1+scan2); writes
//                 'scanned' with the global base already folded in
//   k_place     : deterministic placement of packed (dstlow|src) into bins
//   k_sort_accum: per-bin LDS counting sort by dstlow + fused accumulation
//                 (R8-proven structure + dst-row prefetch under the sort)
// Fallback: R1-style pure-atomic kernel if constraints unmet.

#define CCH 128
#define BSHIFT 5
#define BWIDTH 32              // nodes per bin
#define MAXBIN 4096            // supports N <= 131072 (17-bit src pack)
#define CH 8192                // edges per partition block
#define LDSCAP 1280            // max edges staged per bin (mean ~512)
#define TBINS 16               // bins per pscan block
#define NBLKCAP 256            // max partition blocks supported by pscan tile

// ---------------- fused fp16 pack + per-block bin histogram ----------------

__global__ __launch_bounds__(256) void k_pack_hist(
    const float* __restrict__ x, __half* __restrict__ xh, int n4, int nPack,
    const int* __restrict__ dst, int E, int NBIN, int* __restrict__ hist_bm)
{
    __shared__ int cnt[MAXBIN];
    const int tid = threadIdx.x;

    if (blockIdx.x < nPack) {                 // pack role
        const int i = blockIdx.x * 256 + tid;
        if (i < n4) {
            float4 v = reinterpret_cast<const float4*>(x)[i];
            __half2* o = reinterpret_cast<__half2*>(xh) + (size_t)i * 2;
            o[0] = __floats2half2_rn(v.x, v.y);
            o[1] = __floats2half2_rn(v.z, v.w);
        }
        return;
    }

    const int blk = blockIdx.x - nPack;       // histogram role
    for (int b = tid; b < NBIN; b += 256) cnt[b] = 0;
    __syncthreads();

    const int e0 = blk * CH;
    #pragma unroll
    for (int k = 0; k < CH / 1024; ++k) {
        const int g = (e0 >> 2) + k * 256 + tid;   // int4 index
        const int e = g << 2;
        if (e >= E) continue;
        if (e + 4 <= E) {
            const int4 d4 = reinterpret_cast<const int4*>(dst)[g];
            atomicAdd(&cnt[d4.x >> BSHIFT], 1);
            atomicAdd(&cnt[d4.y >> BSHIFT], 1);
            atomicAdd(&cnt[d4.z >> BSHIFT], 1);
            atomicAdd(&cnt[d4.w >> BSHIFT], 1);
        } else {
            for (int ee = e; ee < E; ++ee) atomicAdd(&cnt[dst[ee] >> BSHIFT], 1);
        }
    }
    __syncthreads();
    int* hb = hist_bm + (size_t)blk * NBIN;   // block-major, coalesced writes
    for (int b = tid; b < NBIN; b += 256) hb[b] = cnt[b];
}

// ---------------- single-pass scan with decoupled lookback ----------------
// Block handles TBINS consecutive bins (a contiguous flat range of the
// bin-major [NBIN][NBLK] matrix). LDS-tiled transposed loads, 256-thread
// Hillis-Steele, then lookback over predecessor blocks via packed
// flag|value words (device scope). scanned[] gets global offsets directly.

__global__ __launch_bounds__(256) void k_pscan(
    const int* __restrict__ hist_bm, int NBIN, int NBLK, int E_unused,
    int* __restrict__ scanned, unsigned int* __restrict__ status)
{
    __shared__ int tile[TBINS][NBLKCAP + 1];
    __shared__ int sdata[256];
    __shared__ int sbase;
    const int t = threadIdx.x;
    const int B0 = blockIdx.x * TBINS;

    for (int g = t; g < TBINS * (NBLKCAP + 1); g += 256)
        (&tile[0][0])[g] = 0;
    __syncthreads();

    for (int g = t; g < NBLK * TBINS; g += 256) {
        const int blk = g >> 4;               // g / TBINS
        const int tb  = g & (TBINS - 1);
        const int bin = B0 + tb;
        if (bin < NBIN) tile[tb][blk] = hist_bm[(size_t)blk * NBIN + bin];
    }
    __syncthreads();

    // thread t covers row tb = t>>4, blks bk0..bk0+15
    const int tb  = t >> 4;
    const int bk0 = (t & 15) * 16;
    int v[16];
    int local = 0;
    #pragma unroll
    for (int k = 0; k < 16; ++k) { v[k] = tile[tb][bk0 + k]; local += v[k]; }

    sdata[t] = local;
    __syncthreads();
    #pragma unroll
    for (int off = 1; off < 256; off <<= 1) {
        int val = (t >= off) ? sdata[t - off] : 0;
        __syncthreads();
        sdata[t] += val;
        __syncthreads();
    }
    const int incl = sdata[t];
    const int total = sdata[255];

    // lookback: publish aggregate, sum predecessors, publish inclusive prefix
    if (t == 0) {
        __hip_atomic_store(&status[blockIdx.x], (1u << 30) | (unsigned)total,
                           __ATOMIC_RELAXED, __HIP_MEMORY_SCOPE_AGENT);
        int base = 0;
        for (int j = (int)blockIdx.x - 1; j >= 0; --j) {
            unsigned w;
            do {
                w = __hip_atomic_load(&status[j], __ATOMIC_RELAXED,
                                      __HIP_MEMORY_SCOPE_AGENT);
            } while ((w >> 30) == 0u);
            base += (int)(w & 0x3FFFFFFFu);
            if ((w >> 30) == 2u) break;       // predecessor had full prefix
        }
        __hip_atomic_store(&status[blockIdx.x],
                           (2u << 30) | (unsigned)(base + total),
                           __ATOMIC_RELAXED, __HIP_MEMORY_SCOPE_AGENT);
        sbase = base;
    }
    __syncthreads();

    int run = sbase + (incl - local);
    const int bin = B0 + tb;
    if (bin < NBIN) {
        #pragma unroll
        for (int k = 0; k < 16; ++k) {
            const int blk = bk0 + k;
            if (blk < NBLK) scanned[(size_t)bin * NBLK + blk] = run;
            run += v[k];
        }
    }
}

// ---------------- deterministic placement ----------------

__global__ __launch_bounds__(256) void k_place(
    const int* __restrict__ src, const int* __restrict__ dst, int E, int NBIN, int NBLK,
    const int* __restrict__ scanned, unsigned int* __restrict__ coarse)
{
    __shared__ int lcur[MAXBIN];
    const int blk = blockIdx.x;
    const int tid = threadIdx.x;
    for (int b = tid; b < NBIN; b += 256)
        lcur[b] = scanned[(size_t)b * NBLK + blk];
    __syncthreads();

    const int e0 = blk * CH;
    #pragma unroll
    for (int k = 0; k < CH / 1024; ++k) {
        const int g = (e0 >> 2) + k * 256 + tid;
        const int e = g << 2;
        if (e >= E) continue;
        if (e + 4 <= E) {
            const int4 d4 = reinterpret_cast<const int4*>(dst)[g];
            const int4 s4 = reinterpret_cast<const int4*>(src)[g];
            int p;
            p = atomicAdd(&lcur[d4.x >> BSHIFT], 1);
            coarse[p] = (unsigned)s4.x | ((unsigned)(d4.x & (BWIDTH - 1)) << 17);
            p = atomicAdd(&lcur[d4.y >> BSHIFT], 1);
            coarse[p] = (unsigned)s4.y | ((unsigned)(d4.y & (BWIDTH - 1)) << 17);
            p = atomicAdd(&lcur[d4.z >> BSHIFT], 1);
            coarse[p] = (unsigned)s4.z | ((unsigned)(d4.z & (BWIDTH - 1)) << 17);
            p = atomicAdd(&lcur[d4.w >> BSHIFT], 1);
            coarse[p] = (unsigned)s4.w | ((unsigned)(d4.w & (BWIDTH - 1)) << 17);
        } else {
            for (int ee = e; ee < E; ++ee) {
                const int d = dst[ee], s = src[ee];
                int p = atomicAdd(&lcur[d >> BSHIFT], 1);
                coarse[p] = (unsigned)s | ((unsigned)(d & (BWIDTH - 1)) << 17);
            }
        }
    }
}

// ---------------- per-bin LDS counting sort + fused accumulation ----------------
// R8 structure: 16 groups of 16 lanes; group gid owns nodes gid*2, gid*2+1.
// Lane sl owns channels sl*8..sl*8+7 (16B fp16 loads). 4-deep gather ladder.
// New: the group's two dst rows are prefetched before the sort barriers.

__global__ __launch_bounds__(256) void k_sort_accum(
    const __half* __restrict__ xh,
    const float* __restrict__ W2,
    const float* __restrict__ W3,
    const unsigned int* __restrict__ coarse,
    const int* __restrict__ scanned,
    int NBIN, int NBLK, int E, int N,
    float* __restrict__ out)
{
    __shared__ unsigned int raw[LDSCAP];
    __shared__ int srcl[LDSCAP];
    __shared__ int cnt[BWIDTH], offs[BWIDTH], cur[BWIDTH];

    const int bin  = blockIdx.x;
    const int tid  = threadIdx.x;
    const int lane = tid & 63;
    const int grp  = lane >> 4;
    const int sl   = lane & 15;
    const int gid  = (tid >> 6) * 4 + grp;
    const int choff = sl << 4;
    const char* xb = (const char*)xh;

    union H { int4 i4; __half2 h[4]; };

    // prefetch this group's two dst rows (latency hidden under the sort)
    const int node0 = (bin << BSHIFT) + gid * 2;
    const int node1 = node0 + 1;
    H uD0, uD1;
    uD0.i4 = make_int4(0, 0, 0, 0);
    uD1.i4 = make_int4(0, 0, 0, 0);
    if (node0 < N) uD0.i4 = *reinterpret_cast<const int4*>(xb + (((size_t)node0) << 8) + choff);
    if (node1 < N) uD1.i4 = *reinterpret_cast<const int4*>(xb + (((size_t)node1) << 8) + choff);

    const size_t i0 = (size_t)bin * NBLK;
    const int beg = scanned[i0];
    const int end = (bin + 1 < NBIN) ? scanned[i0 + NBLK] : E;
    const int mtot = end - beg;
    const int m = (mtot < LDSCAP) ? mtot : LDSCAP;

    if (tid < BWIDTH) cnt[tid] = 0;
    __syncthreads();

    for (int i = tid; i < m; i += 256) {
        unsigned u = coarse[beg + i];
        raw[i] = u;
        atomicAdd(&cnt[u >> 17], 1);
    }
    __syncthreads();

    if (tid < BWIDTH) {                       // lanes 0..31 of wave 0
        int c = cnt[tid];
        int v = c;
        #pragma unroll
        for (int d2 = 1; d2 < BWIDTH; d2 <<= 1) {
            int t2 = __shfl_up(v, d2, 64);
            if (tid >= d2) v += t2;
        }
        offs[tid] = v - c;
        cur[tid]  = v - c;
    }
    __syncthreads();

    for (int i = tid; i < m; i += 256) {
        const unsigned u = raw[i];
        const int p = atomicAdd(&cur[u >> 17], 1);
        srcl[p] = (int)(u & 0x1FFFFu);
    }
    __syncthreads();

    const float4 w3a = *reinterpret_cast<const float4*>(W3 + sl * 8);
    const float4 w3b = *reinterpret_cast<const float4*>(W3 + sl * 8 + 4);
    const float4 w2a = *reinterpret_cast<const float4*>(W2 + sl * 8);
    const float4 w2b = *reinterpret_cast<const float4*>(W2 + sl * 8 + 4);

    #pragma unroll
    for (int i = 0; i < 2; ++i) {
        const int node = (i == 0) ? node0 : node1;
        if (node >= N) continue;
        const int dl = gid * 2 + i;
        const H uD = (i == 0) ? uD0 : uD1;

        const float2 e0 = __half22float2(uD.h[0]);
        const float2 e1 = __half22float2(uD.h[1]);
        const float2 e2 = __half22float2(uD.h[2]);
        const float2 e3 = __half22float2(uD.h[3]);
        const float4 va = make_float4(w3a.x * e0.x, w3a.y * e0.y,
                                      w3a.z * e1.x, w3a.w * e1.y);
        const float4 vb = make_float4(w3b.x * e2.x, w3b.y * e2.y,
                                      w3b.z * e3.x, w3b.w * e3.y);

        float4 accA = make_float4(0.f, 0.f, 0.f, 0.f);
        float4 accB = make_float4(0.f, 0.f, 0.f, 0.f);

        const int b0 = offs[dl];
        const int c  = cnt[dl];

        int j = 0;
        for (; j + 4 <= c; j += 4) {          // 4 gathers in flight per group
            const int s0 = srcl[b0 + j];
            const int s1 = srcl[b0 + j + 1];
            const int s2 = srcl[b0 + j + 2];
            const int s3 = srcl[b0 + j + 3];
            H u0, u1, u2, u3;
            u0.i4 = *reinterpret_cast<const int4*>(xb + (((size_t)s0) << 8) + choff);
            u1.i4 = *reinterpret_cast<const int4*>(xb + (((size_t)s1) << 8) + choff);
            u2.i4 = *reinterpret_cast<const int4*>(xb + (((size_t)s2) << 8) + choff);
            u3.i4 = *reinterpret_cast<const int4*>(xb + (((size_t)s3) << 8) + choff);
            const float2 f00 = __half22float2(u0.h[0]);
            const float2 f01 = __half22float2(u0.h[1]);
            const float2 f02 = __half22float2(u0.h[2]);
            const float2 f03 = __half22float2(u0.h[3]);
            const float2 f10 = __half22float2(u1.h[0]);
            const float2 f11 = __half22float2(u1.h[1]);
            const float2 f12 = __half22float2(u1.h[2]);
            const float2 f13 = __half22float2(u1.h[3]);
            const float2 f20 = __half22float2(u2.h[0]);
            const float2 f21 = __half22float2(u2.h[1]);
            const float2 f22 = __half22float2(u2.h[2]);
            const float2 f23 = __half22float2(u2.h[3]);
            const float2 f30 = __half22float2(u3.h[0]);
            const float2 f31 = __half22float2(u3.h[1]);
            const float2 f32 = __half22float2(u3.h[2]);
            const float2 f33 = __half22float2(u3.h[3]);
            float p0 = f00.x * va.x + f00.y * va.y + f01.x * va.z + f01.y * va.w
                     + f02.x * vb.x + f02.y * vb.y + f03.x * vb.z + f03.y * vb.w;
            float p1 = f10.x * va.x + f10.y * va.y + f11.x * va.z + f11.y * va.w
                     + f12.x * vb.x + f12.y * vb.y + f13.x * vb.z + f13.y * vb.w;
            float p2 = f20.x * va.x + f20.y * va.y + f21.x * va.z + f21.y * va.w
                     + f22.x * vb.x + f22.y * vb.y + f23.x * vb.z + f23.y * vb.w;
            float p3 = f30.x * va.x + f30.y * va.y + f31.x * va.z + f31.y * va.w
                     + f32.x * vb.x + f32.y * vb.y + f33.x * vb.z + f33.y * vb.w;
            #pragma unroll
            for (int off = 1; off < 16; off <<= 1) {   // within-group reduce
                p0 += __shfl_xor(p0, off, 64);
                p1 += __shfl_xor(p1, off, 64);
                p2 += __shfl_xor(p2, off, 64);
                p3 += __shfl_xor(p3, off, 64);
            }
            accA.x += p0 * f00.x + p1 * f10.x + p2 * f20.x + p3 * f30.x;
            accA.y += p0 * f00.y + p1 * f10.y + p2 * f20.y + p3 * f30.y;
            accA.z += p0 * f01.x + p1 * f11.x + p2 * f21.x + p3 * f31.x;
            accA.w += p0 * f01.y + p1 * f11.y + p2 * f21.y + p3 * f31.y;
            accB.x += p0 * f02.x + p1 * f12.x + p2 * f22.x + p3 * f32.x;
            accB.y += p0 * f02.y + p1 * f12.y + p2 * f22.y + p3 * f32.y;
            accB.z += p0 * f03.x + p1 * f13.x + p2 * f23.x + p3 * f33.x;
            accB.w += p0 * f03.y + p1 * f13.y + p2 * f23.y + p3 * f33.y;
        }
        for (; j < c; ++j) {                  // remainder, whole group active
            H u0;
            u0.i4 = *reinterpret_cast<const int4*>(
                xb + (((size_t)srcl[b0 + j]) << 8) + choff);
            const float2 f0 = __half22float2(u0.h[0]);
            const float2 f1 = __half22float2(u0.h[1]);
            const float2 f2 = __half22float2(u0.h[2]);
            const float2 f3 = __half22float2(u0.h[3]);
            float p = f0.x * va.x + f0.y * va.y + f1.x * va.z + f1.y * va.w
                    + f2.x * vb.x + f2.y * vb.y + f3.x * vb.z + f3.y * vb.w;
            #pragma unroll
            for (int off = 1; off < 16; off <<= 1) p += __shfl_xor(p, off, 64);
            accA.x += p * f0.x; accA.y += p * f0.y;
            accA.z += p * f1.x; accA.w += p * f1.y;
            accB.x += p * f2.x; accB.y += p * f2.y;
            accB.z += p * f3.x; accB.w += p * f3.y;
        }
        // LDS-capacity overflow (normally zero iterations)
        for (int i2 = LDSCAP; i2 < mtot; ++i2) {
            const unsigned u = coarse[beg + i2];
            if ((int)(u >> 17) != dl) continue;
            H u0;
            u0.i4 = *reinterpret_cast<const int4*>(
                xb + (((size_t)(u & 0x1FFFFu)) << 8) + choff);
            const float2 f0 = __half22float2(u0.h[0]);
            const float2 f1 = __half22float2(u0.h[1]);
            const float2 f2 = __half22float2(u0.h[2]);
            const float2 f3 = __half22float2(u0.h[3]);
            float p = f0.x * va.x + f0.y * va.y + f1.x * va.z + f1.y * va.w
                    + f2.x * vb.x + f2.y * vb.y + f3.x * vb.z + f3.y * vb.w;
            #pragma unroll
            for (int off = 1; off < 16; off <<= 1) p += __shfl_xor(p, off, 64);
            accA.x += p * f0.x; accA.y += p * f0.y;
            accA.z += p * f1.x; accA.w += p * f1.y;
            accB.x += p * f2.x; accB.y += p * f2.y;
            accB.z += p * f3.x; accB.w += p * f3.y;
        }

        accA.x *= w2a.x; accA.y *= w2a.y; accA.z *= w2a.z; accA.w *= w2a.w;
        accB.x *= w2b.x; accB.y *= w2b.y; accB.z *= w2b.z; accB.w *= w2b.w;
        float* orow = out + (size_t)node * CCH + sl * 8;
        *reinterpret_cast<float4*>(orow)     = accA;
        *reinterpret_cast<float4*>(orow + 4) = accB;
    }
}

// ---------------- last-resort fallback: pure fp32 atomics (R1) ----------------

__global__ __launch_bounds__(256) void edge_gather_scatter(
    const float* __restrict__ x, const int* __restrict__ edge_index,
    const float* __restrict__ W2, const float* __restrict__ W3,
    float* __restrict__ out, int E)
{
    const int e    = (blockIdx.x * blockDim.x + threadIdx.x) >> 6;
    const int lane = threadIdx.x & 63;
    if (e >= E) return;
    const int s = edge_index[e];
    const int d = edge_index[E + e];
    const float2 xs = *reinterpret_cast<const float2*>(x + (size_t)s * CCH + lane * 2);
    const float2 xd = *reinterpret_cast<const float2*>(x + (size_t)d * CCH + lane * 2);
    const float2 w3 = *reinterpret_cast<const float2*>(W3 + lane * 2);
    const float2 w2 = *reinterpret_cast<const float2*>(W2 + lane * 2);
    float p = xs.x * w3.x * xd.x + xs.y * w3.y * xd.y;
    #pragma unroll
    for (int off = 32; off > 0; off >>= 1) p += __shfl_xor(p, off, 64);
    float* o = out + (size_t)d * CCH + lane * 2;
    atomicAdd(o,     p * xs.x * w2.x);
    atomicAdd(o + 1, p * xs.y * w2.y);
}

// ---------------- launch ----------------

extern "C" void kernel_launch(void* const* d_in, const int* in_sizes, int n_in,
                              void* d_out, int out_size, void* d_ws, size_t ws_size,
                              hipStream_t stream) {
    const float* x          = (const float*)d_in[0];
    const int*   edge_index = (const int*)  d_in[1];
    const float* W2         = (const float*)d_in[2];
    const float* W3         = (const float*)d_in[3];
    float*       out        = (float*)d_out;

    const int E = in_sizes[1] / 2;
    const int N = out_size / CCH;
    const int* src = edge_index;
    const int* dst = edge_index + E;

    const int NBIN = (N + BWIDTH - 1) >> BSHIFT;
    const int NBLK = (E + CH - 1) / CH;
    const long long Mll = (long long)NBIN * NBLK;
    const int M = (int)Mll;
    const int nb1 = (NBIN + TBINS - 1) / TBINS;

    const size_t xh_bytes = (size_t)N * CCH * 2;
    const size_t need = xh_bytes + (size_t)E * 4 + 2 * (size_t)M * 4 + 4096;

    const bool aligned16 = (((uintptr_t)src & 15) == 0) && (((uintptr_t)dst & 15) == 0);

    if (N <= (1 << 17) && NBIN <= MAXBIN && NBLK <= NBLKCAP && Mll <= (1LL << 20) &&
        nb1 <= 1024 && aligned16 && ws_size >= need) {
        char* base = (char*)d_ws;
        __half* xh        = (__half*)base;       base += xh_bytes;
        unsigned* coarse  = (unsigned*)base;     base += (size_t)E * 4;
        int* hist_bm      = (int*)base;          base += (size_t)M * 4;
        int* scanned      = (int*)base;          base += (size_t)M * 4;
        unsigned* status  = (unsigned*)base;     // 1024 x u32

        const int n4 = N * CCH / 4;
        const int nPack = (n4 + 255) / 256;

        hipMemsetAsync(status, 0, 1024 * sizeof(unsigned), stream);
        k_pack_hist<<<nPack + NBLK, 256, 0, stream>>>(x, xh, n4, nPack,
                                                      dst, E, NBIN, hist_bm);
        k_pscan<<<nb1, 256, 0, stream>>>(hist_bm, NBIN, NBLK, E, scanned, status);
        k_place<<<NBLK, 256, 0, stream>>>(src, dst, E, NBIN, NBLK, scanned, coarse);
        k_sort_accum<<<NBIN, 256, 0, stream>>>(xh, W2, W3, coarse, scanned,
                                               NBIN, NBLK, E, N, out);
        return;
    }

    // last resort: pure atomics
    hipMemsetAsync(d_out, 0, (size_t)out_size * sizeof(float), stream);
    const int grid = (E * 64 + 255) / 256;
    edge_gather_scatter<<<grid, 256, 0, stream>>>(x, edge_index, W2, W3, out, E);
}

// Round 11
// 126.883 us; speedup vs baseline: 1.0978x; 1.0978x over previous
//
#include <hip/hip_runtime.h>
#include <hip/hip_fp16.h>

// out[n,c] = sum_{e: dst[e]==n} ( sum_k x[src[e],k]*W3[k]*x[dst[e],k] ) * x[src[e],c] * W2[c]
// B=1, N=100000, E=1600000, C=128.
//
// Pipeline (5 launches; pack moved OFF the critical path):
//   k_hist      : per-block coarse-bin histogram (bin = dst>>5), block-major out
//   k_pscan1/2  : exclusive scan of bin-major (bin,block) counts (LDS-tiled)
//   k_pack_place: fused; place-role blocks (deterministic placement of packed
//                 (dstlow|src) into bins) + pack-role blocks (x fp32->fp16)
//                 run concurrently — pack is only needed by k_sort_accum
//   k_sort_accum: per-bin LDS counting sort by dstlow + fused accumulation
//                 (R10-proven: 16-lane groups, 4-deep ladder, dst prefetch)
// Fallback: R1-style pure-atomic kernel if constraints unmet.

#define CCH 128
#define BSHIFT 5
#define BWIDTH 32              // nodes per bin
#define MAXBIN 4096            // supports N <= 131072 (17-bit src pack)
#define CH 8192                // edges per partition block
#define LDSCAP 1280            // max edges staged per bin (mean ~512)
#define TBINS 16               // bins per pscan1 block
#define NBLKCAP 256            // max partition blocks supported by pscan1 tile

// ---------------- per-block bin histogram ----------------

__global__ __launch_bounds__(256) void k_hist(
    const int* __restrict__ dst, int E, int NBIN, int* __restrict__ hist_bm)
{
    __shared__ int cnt[MAXBIN];
    const int blk = blockIdx.x;
    const int tid = threadIdx.x;
    for (int b = tid; b < NBIN; b += 256) cnt[b] = 0;
    __syncthreads();

    const int e0 = blk * CH;
    #pragma unroll
    for (int k = 0; k < CH / 1024; ++k) {
        const int g = (e0 >> 2) + k * 256 + tid;   // int4 index
        const int e = g << 2;
        if (e >= E) continue;
        if (e + 4 <= E) {
            const int4 d4 = reinterpret_cast<const int4*>(dst)[g];
            atomicAdd(&cnt[d4.x >> BSHIFT], 1);
            atomicAdd(&cnt[d4.y >> BSHIFT], 1);
            atomicAdd(&cnt[d4.z >> BSHIFT], 1);
            atomicAdd(&cnt[d4.w >> BSHIFT], 1);
        } else {
            for (int ee = e; ee < E; ++ee) atomicAdd(&cnt[dst[ee] >> BSHIFT], 1);
        }
    }
    __syncthreads();
    int* hb = hist_bm + (size_t)blk * NBIN;   // block-major, coalesced writes
    for (int b = tid; b < NBIN; b += 256) hb[b] = cnt[b];
}

// ---------------- scan: LDS-tiled transpose, coalesced reads ----------------

__global__ __launch_bounds__(256) void k_pscan1(
    const int* __restrict__ hist_bm, int NBIN, int NBLK,
    int* __restrict__ partial, int* __restrict__ blocksum)
{
    __shared__ int tile[TBINS][NBLKCAP + 1];
    __shared__ int sdata[256];
    const int t = threadIdx.x;
    const int B0 = blockIdx.x * TBINS;

    for (int g = t; g < TBINS * (NBLKCAP + 1); g += 256)
        (&tile[0][0])[g] = 0;
    __syncthreads();

    for (int g = t; g < NBLK * TBINS; g += 256) {
        const int blk = g >> 4;               // g / TBINS
        const int tb  = g & (TBINS - 1);
        const int bin = B0 + tb;
        if (bin < NBIN) tile[tb][blk] = hist_bm[(size_t)blk * NBIN + bin];
    }
    __syncthreads();

    const int tb  = t >> 4;
    const int bk0 = (t & 15) * 16;
    int v[16];
    int local = 0;
    #pragma unroll
    for (int k = 0; k < 16; ++k) { v[k] = tile[tb][bk0 + k]; local += v[k]; }

    sdata[t] = local;
    __syncthreads();
    #pragma unroll
    for (int off = 1; off < 256; off <<= 1) {
        int val = (t >= off) ? sdata[t - off] : 0;
        __syncthreads();
        sdata[t] += val;
        __syncthreads();
    }
    const int incl = sdata[t];
    int run = incl - local;
    if (t == 255) blocksum[blockIdx.x] = incl;

    const int bin = B0 + tb;
    if (bin < NBIN) {
        #pragma unroll
        for (int k = 0; k < 16; ++k) {
            const int blk = bk0 + k;
            if (blk < NBLK) partial[(size_t)bin * NBLK + blk] = run;
            run += v[k];
        }
    }
}

__global__ void k_scan2(int* __restrict__ blocksum, int nb) {
    __shared__ int sdata[1024];
    const int t = threadIdx.x;
    const int v = (t < nb) ? blocksum[t] : 0;
    sdata[t] = v;
    __syncthreads();
    for (int off = 1; off < 1024; off <<= 1) {
        int val = (t >= off) ? sdata[t - off] : 0;
        __syncthreads();
        sdata[t] += val;
        __syncthreads();
    }
    if (t < nb) blocksum[t] = sdata[t] - v;
}

// ---------------- fused pack + deterministic placement ----------------
// blocks [0, NBLK)        : place role
// blocks [NBLK, NBLK+nP)  : pack role (x fp32 -> fp16)

__global__ __launch_bounds__(256) void k_pack_place(
    const float* __restrict__ x, __half* __restrict__ xh, int n4,
    const int* __restrict__ src, const int* __restrict__ dst, int E,
    int NBIN, int NBLK,
    const int* __restrict__ partial, const int* __restrict__ blocksum,
    unsigned int* __restrict__ coarse)
{
    __shared__ int lcur[MAXBIN];
    const int tid = threadIdx.x;

    if (blockIdx.x >= (unsigned)NBLK) {       // pack role
        const int i = (blockIdx.x - NBLK) * 256 + tid;
        if (i < n4) {
            float4 v = reinterpret_cast<const float4*>(x)[i];
            __half2* o = reinterpret_cast<__half2*>(xh) + (size_t)i * 2;
            o[0] = __floats2half2_rn(v.x, v.y);
            o[1] = __floats2half2_rn(v.z, v.w);
        }
        return;
    }

    const int blk = blockIdx.x;               // place role
    for (int b = tid; b < NBIN; b += 256) {
        lcur[b] = partial[(size_t)b * NBLK + blk] + blocksum[b / TBINS];
    }
    __syncthreads();

    const int e0 = blk * CH;
    #pragma unroll
    for (int k = 0; k < CH / 1024; ++k) {
        const int g = (e0 >> 2) + k * 256 + tid;
        const int e = g << 2;
        if (e >= E) continue;
        if (e + 4 <= E) {
            const int4 d4 = reinterpret_cast<const int4*>(dst)[g];
            const int4 s4 = reinterpret_cast<const int4*>(src)[g];
            int p;
            p = atomicAdd(&lcur[d4.x >> BSHIFT], 1);
            coarse[p] = (unsigned)s4.x | ((unsigned)(d4.x & (BWIDTH - 1)) << 17);
            p = atomicAdd(&lcur[d4.y >> BSHIFT], 1);
            coarse[p] = (unsigned)s4.y | ((unsigned)(d4.y & (BWIDTH - 1)) << 17);
            p = atomicAdd(&lcur[d4.z >> BSHIFT], 1);
            coarse[p] = (unsigned)s4.z | ((unsigned)(d4.z & (BWIDTH - 1)) << 17);
            p = atomicAdd(&lcur[d4.w >> BSHIFT], 1);
            coarse[p] = (unsigned)s4.w | ((unsigned)(d4.w & (BWIDTH - 1)) << 17);
        } else {
            for (int ee = e; ee < E; ++ee) {
                const int d = dst[ee], s = src[ee];
                int p = atomicAdd(&lcur[d >> BSHIFT], 1);
                coarse[p] = (unsigned)s | ((unsigned)(d & (BWIDTH - 1)) << 17);
            }
        }
    }
}

// ---------------- per-bin LDS counting sort + fused accumulation ----------------
// 16 groups of 16 lanes; group gid owns nodes gid*2, gid*2+1. Lane sl owns
// channels sl*8..sl*8+7 (16B fp16 loads). 4-deep gather ladder; dst rows
// prefetched before the sort barriers.

__global__ __launch_bounds__(256) void k_sort_accum(
    const __half* __restrict__ xh,
    const float* __restrict__ W2,
    const float* __restrict__ W3,
    const unsigned int* __restrict__ coarse,
    const int* __restrict__ partial, const int* __restrict__ blocksum,
    int NBIN, int NBLK, int E, int N,
    float* __restrict__ out)
{
    __shared__ unsigned int raw[LDSCAP];
    __shared__ int srcl[LDSCAP];
    __shared__ int cnt[BWIDTH], offs[BWIDTH], cur[BWIDTH];

    const int bin  = blockIdx.x;
    const int tid  = threadIdx.x;
    const int lane = tid & 63;
    const int grp  = lane >> 4;
    const int sl   = lane & 15;
    const int gid  = (tid >> 6) * 4 + grp;
    const int choff = sl << 4;
    const char* xb = (const char*)xh;

    union H { int4 i4; __half2 h[4]; };

    // prefetch this group's two dst rows (latency hidden under the sort)
    const int node0 = (bin << BSHIFT) + gid * 2;
    const int node1 = node0 + 1;
    H uD0, uD1;
    uD0.i4 = make_int4(0, 0, 0, 0);
    uD1.i4 = make_int4(0, 0, 0, 0);
    if (node0 < N) uD0.i4 = *reinterpret_cast<const int4*>(xb + (((size_t)node0) << 8) + choff);
    if (node1 < N) uD1.i4 = *reinterpret_cast<const int4*>(xb + (((size_t)node1) << 8) + choff);

    const size_t i0 = (size_t)bin * NBLK;
    const int beg = partial[i0] + blocksum[bin / TBINS];
    const int end = (bin + 1 < NBIN)
        ? partial[i0 + NBLK] + blocksum[(bin + 1) / TBINS] : E;
    const int mtot = end - beg;
    const int m = (mtot < LDSCAP) ? mtot : LDSCAP;

    if (tid < BWIDTH) cnt[tid] = 0;
    __syncthreads();

    for (int i = tid; i < m; i += 256) {
        unsigned u = coarse[beg + i];
        raw[i] = u;
        atomicAdd(&cnt[u >> 17], 1);
    }
    __syncthreads();

    if (tid < BWIDTH) {                       // lanes 0..31 of wave 0
        int c = cnt[tid];
        int v = c;
        #pragma unroll
        for (int d2 = 1; d2 < BWIDTH; d2 <<= 1) {
            int t2 = __shfl_up(v, d2, 64);
            if (tid >= d2) v += t2;
        }
        offs[tid] = v - c;
        cur[tid]  = v - c;
    }
    __syncthreads();

    for (int i = tid; i < m; i += 256) {
        const unsigned u = raw[i];
        const int p = atomicAdd(&cur[u >> 17], 1);
        srcl[p] = (int)(u & 0x1FFFFu);
    }
    __syncthreads();

    const float4 w3a = *reinterpret_cast<const float4*>(W3 + sl * 8);
    const float4 w3b = *reinterpret_cast<const float4*>(W3 + sl * 8 + 4);
    const float4 w2a = *reinterpret_cast<const float4*>(W2 + sl * 8);
    const float4 w2b = *reinterpret_cast<const float4*>(W2 + sl * 8 + 4);

    #pragma unroll
    for (int i = 0; i < 2; ++i) {
        const int node = (i == 0) ? node0 : node1;
        if (node >= N) continue;
        const int dl = gid * 2 + i;
        const H uD = (i == 0) ? uD0 : uD1;

        const float2 e0 = __half22float2(uD.h[0]);
        const float2 e1 = __half22float2(uD.h[1]);
        const float2 e2 = __half22float2(uD.h[2]);
        const float2 e3 = __half22float2(uD.h[3]);
        const float4 va = make_float4(w3a.x * e0.x, w3a.y * e0.y,
                                      w3a.z * e1.x, w3a.w * e1.y);
        const float4 vb = make_float4(w3b.x * e2.x, w3b.y * e2.y,
                                      w3b.z * e3.x, w3b.w * e3.y);

        float4 accA = make_float4(0.f, 0.f, 0.f, 0.f);
        float4 accB = make_float4(0.f, 0.f, 0.f, 0.f);

        const int b0 = offs[dl];
        const int c  = cnt[dl];

        int j = 0;
        for (; j + 4 <= c; j += 4) {          // 4 gathers in flight per group
            const int s0 = srcl[b0 + j];
            const int s1 = srcl[b0 + j + 1];
            const int s2 = srcl[b0 + j + 2];
            const int s3 = srcl[b0 + j + 3];
            H u0, u1, u2, u3;
            u0.i4 = *reinterpret_cast<const int4*>(xb + (((size_t)s0) << 8) + choff);
            u1.i4 = *reinterpret_cast<const int4*>(xb + (((size_t)s1) << 8) + choff);
            u2.i4 = *reinterpret_cast<const int4*>(xb + (((size_t)s2) << 8) + choff);
            u3.i4 = *reinterpret_cast<const int4*>(xb + (((size_t)s3) << 8) + choff);
            const float2 f00 = __half22float2(u0.h[0]);
            const float2 f01 = __half22float2(u0.h[1]);
            const float2 f02 = __half22float2(u0.h[2]);
            const float2 f03 = __half22float2(u0.h[3]);
            const float2 f10 = __half22float2(u1.h[0]);
            const float2 f11 = __half22float2(u1.h[1]);
            const float2 f12 = __half22float2(u1.h[2]);
            const float2 f13 = __half22float2(u1.h[3]);
            const float2 f20 = __half22float2(u2.h[0]);
            const float2 f21 = __half22float2(u2.h[1]);
            const float2 f22 = __half22float2(u2.h[2]);
            const float2 f23 = __half22float2(u2.h[3]);
            const float2 f30 = __half22float2(u3.h[0]);
            const float2 f31 = __half22float2(u3.h[1]);
            const float2 f32 = __half22float2(u3.h[2]);
            const float2 f33 = __half22float2(u3.h[3]);
            float p0 = f00.x * va.x + f00.y * va.y + f01.x * va.z + f01.y * va.w
                     + f02.x * vb.x + f02.y * vb.y + f03.x * vb.z + f03.y * vb.w;
            float p1 = f10.x * va.x + f10.y * va.y + f11.x * va.z + f11.y * va.w
                     + f12.x * vb.x + f12.y * vb.y + f13.x * vb.z + f13.y * vb.w;
            float p2 = f20.x * va.x + f20.y * va.y + f21.x * va.z + f21.y * va.w
                     + f22.x * vb.x + f22.y * vb.y + f23.x * vb.z + f23.y * vb.w;
            float p3 = f30.x * va.x + f30.y * va.y + f31.x * va.z + f31.y * va.w
                     + f32.x * vb.x + f32.y * vb.y + f33.x * vb.z + f33.y * vb.w;
            #pragma unroll
            for (int off = 1; off < 16; off <<= 1) {   // within-group reduce
                p0 += __shfl_xor(p0, off, 64);
                p1 += __shfl_xor(p1, off, 64);
                p2 += __shfl_xor(p2, off, 64);
                p3 += __shfl_xor(p3, off, 64);
            }
            accA.x += p0 * f00.x + p1 * f10.x + p2 * f20.x + p3 * f30.x;
            accA.y += p0 * f00.y + p1 * f10.y + p2 * f20.y + p3 * f30.y;
            accA.z += p0 * f01.x + p1 * f11.x + p2 * f21.x + p3 * f31.x;
            accA.w += p0 * f01.y + p1 * f11.y + p2 * f21.y + p3 * f31.y;
            accB.x += p0 * f02.x + p1 * f12.x + p2 * f22.x + p3 * f32.x;
            accB.y += p0 * f02.y + p1 * f12.y + p2 * f22.y + p3 * f32.y;
            accB.z += p0 * f03.x + p1 * f13.x + p2 * f23.x + p3 * f33.x;
            accB.w += p0 * f03.y + p1 * f13.y + p2 * f23.y + p3 * f33.y;
        }
        for (; j < c; ++j) {                  // remainder, whole group active
            H u0;
            u0.i4 = *reinterpret_cast<const int4*>(
                xb + (((size_t)srcl[b0 + j]) << 8) + choff);
            const float2 f0 = __half22float2(u0.h[0]);
            const float2 f1 = __half22float2(u0.h[1]);
            const float2 f2 = __half22float2(u0.h[2]);
            const float2 f3 = __half22float2(u0.h[3]);
            float p = f0.x * va.x + f0.y * va.y + f1.x * va.z + f1.y * va.w
                    + f2.x * vb.x + f2.y * vb.y + f3.x * vb.z + f3.y * vb.w;
            #pragma unroll
            for (int off = 1; off < 16; off <<= 1) p += __shfl_xor(p, off, 64);
            accA.x += p * f0.x; accA.y += p * f0.y;
            accA.z += p * f1.x; accA.w += p * f1.y;
            accB.x += p * f2.x; accB.y += p * f2.y;
            accB.z += p * f3.x; accB.w += p * f3.y;
        }
        // LDS-capacity overflow (normally zero iterations)
        for (int i2 = LDSCAP; i2 < mtot; ++i2) {
            const unsigned u = coarse[beg + i2];
            if ((int)(u >> 17) != dl) continue;
            H u0;
            u0.i4 = *reinterpret_cast<const int4*>(
                xb + (((size_t)(u & 0x1FFFFu)) << 8) + choff);
            const float2 f0 = __half22float2(u0.h[0]);
            const float2 f1 = __half22float2(u0.h[1]);
            const float2 f2 = __half22float2(u0.h[2]);
            const float2 f3 = __half22float2(u0.h[3]);
            float p = f0.x * va.x + f0.y * va.y + f1.x * va.z + f1.y * va.w
                    + f2.x * vb.x + f2.y * vb.y + f3.x * vb.z + f3.y * vb.w;
            #pragma unroll
            for (int off = 1; off < 16; off <<= 1) p += __shfl_xor(p, off, 64);
            accA.x += p * f0.x; accA.y += p * f0.y;
            accA.z += p * f1.x; accA.w += p * f1.y;
            accB.x += p * f2.x; accB.y += p * f2.y;
            accB.z += p * f3.x; accB.w += p * f3.y;
        }

        accA.x *= w2a.x; accA.y *= w2a.y; accA.z *= w2a.z; accA.w *= w2a.w;
        accB.x *= w2b.x; accB.y *= w2b.y; accB.z *= w2b.z; accB.w *= w2b.w;
        float* orow = out + (size_t)node * CCH + sl * 8;
        *reinterpret_cast<float4*>(orow)     = accA;
        *reinterpret_cast<float4*>(orow + 4) = accB;
    }
}

// ---------------- last-resort fallback: pure fp32 atomics (R1) ----------------

__global__ __launch_bounds__(256) void edge_gather_scatter(
    const float* __restrict__ x, const int* __restrict__ edge_index,
    const float* __restrict__ W2, const float* __restrict__ W3,
    float* __restrict__ out, int E)
{
    const int e    = (blockIdx.x * blockDim.x + threadIdx.x) >> 6;
    const int lane = threadIdx.x & 63;
    if (e >= E) return;
    const int s = edge_index[e];
    const int d = edge_index[E + e];
    const float2 xs = *reinterpret_cast<const float2*>(x + (size_t)s * CCH + lane * 2);
    const float2 xd = *reinterpret_cast<const float2*>(x + (size_t)d * CCH + lane * 2);
    const float2 w3 = *reinterpret_cast<const float2*>(W3 + lane * 2);
    const float2 w2 = *reinterpret_cast<const float2*>(W2 + lane * 2);
    float p = xs.x * w3.x * xd.x + xs.y * w3.y * xd.y;
    #pragma unroll
    for (int off = 32; off > 0; off >>= 1) p += __shfl_xor(p, off, 64);
    float* o = out + (size_t)d * CCH + lane * 2;
    atomicAdd(o,     p * xs.x * w2.x);
    atomicAdd(o + 1, p * xs.y * w2.y);
}

// ---------------- launch ----------------

extern "C" void kernel_launch(void* const* d_in, const int* in_sizes, int n_in,
                              void* d_out, int out_size, void* d_ws, size_t ws_size,
                              hipStream_t stream) {
    const float* x          = (const float*)d_in[0];
    const int*   edge_index = (const int*)  d_in[1];
    const float* W2         = (const float*)d_in[2];
    const float* W3         = (const float*)d_in[3];
    float*       out        = (float*)d_out;

    const int E = in_sizes[1] / 2;
    const int N = out_size / CCH;
    const int* src = edge_index;
    const int* dst = edge_index + E;

    const int NBIN = (N + BWIDTH - 1) >> BSHIFT;
    const int NBLK = (E + CH - 1) / CH;
    const long long Mll = (long long)NBIN * NBLK;
    const int M = (int)Mll;
    const int nb1 = (NBIN + TBINS - 1) / TBINS;

    const size_t xh_bytes = (size_t)N * CCH * 2;
    const size_t need = xh_bytes + (size_t)E * 4 + 2 * (size_t)M * 4 + 1024 * 4;

    const bool aligned16 = (((uintptr_t)src & 15) == 0) && (((uintptr_t)dst & 15) == 0);

    if (N <= (1 << 17) && NBIN <= MAXBIN && NBLK <= NBLKCAP && Mll <= (1LL << 20) &&
        nb1 <= 1024 && aligned16 && ws_size >= need) {
        char* base = (char*)d_ws;
        __half* xh       = (__half*)base;        base += xh_bytes;
        unsigned* coarse = (unsigned*)base;      base += (size_t)E * 4;
        int* hist_bm     = (int*)base;           base += (size_t)M * 4;
        int* partial     = (int*)base;           base += (size_t)M * 4;
        int* blocksum    = (int*)base;

        const int n4 = N * CCH / 4;
        const int nPack = (n4 + 255) / 256;

        k_hist<<<NBLK, 256, 0, stream>>>(dst, E, NBIN, hist_bm);
        k_pscan1<<<nb1, 256, 0, stream>>>(hist_bm, NBIN, NBLK, partial, blocksum);
        k_scan2<<<1, 1024, 0, stream>>>(blocksum, nb1);
        k_pack_place<<<NBLK + nPack, 256, 0, stream>>>(x, xh, n4, src, dst, E,
                                                       NBIN, NBLK,
                                                       partial, blocksum, coarse);
        k_sort_accum<<<NBIN, 256, 0, stream>>>(xh, W2, W3, coarse,
                                               partial, blocksum,
                                               NBIN, NBLK, E, N, out);
        return;
    }

    // last resort: pure atomics
    hipMemsetAsync(d_out, 0, (size_t)out_size * sizeof(float), stream);
    const int grid = (E * 64 + 255) / 256;
    edge_gather_scatter<<<grid, 256, 0, stream>>>(x, edge_index, W2, W3, out, E);
}

// Round 12
// 123.970 us; speedup vs baseline: 1.1236x; 1.0235x over previous
//
#include <hip/hip_runtime.h>
#include <hip/hip_fp16.h>

// out[n,c] = sum_{e: dst[e]==n} ( sum_k x[src[e],k]*W3[k]*x[dst[e],k] ) * x[src[e],c] * W2[c]
// B=1, N=100000, E=1600000, C=128.
//
// Pipeline (4 launches; fp16 pack spread as a co-role across the first three):
//   k_hist_pack : hist-role blocks (coarse-bin histogram, bin=dst>>5) + pack 1/3
//   k_pscan_pack: scan-role blocks (LDS-tiled transpose scan of the bin-major
//                 (bin,block) matrix; blocksum = raw per-scanblock totals) + pack 1/3
//   k_place_pack: place-role blocks (deterministic placement of (dstlow|src);
//                 blocksum prefix folded in via an in-LDS scan) + pack 1/3
//   k_sort_accum: per-bin LDS counting sort + fused accumulation (R10-proven);
//                 blocksum prefix computed per-wave (masked load + shfl reduce)
// Fallback: R1-style pure-atomic kernel if constraints unmet.

#define CCH 128
#define BSHIFT 5
#define BWIDTH 32              // nodes per bin
#define MAXBIN 4096            // supports N <= 131072 (17-bit src pack)
#define CH 8192                // edges per partition block
#define LDSCAP 1280            // max edges staged per bin (mean ~512)
#define TBINS 16               // bins per pscan block
#define NBLKCAP 256            // max partition blocks supported by pscan tile

// ---------------- pack helper (device inline) ----------------

__device__ __forceinline__ void pack_body(const float* __restrict__ x,
                                          __half* __restrict__ xh,
                                          int n4, int i) {
    if (i < n4) {
        float4 v = reinterpret_cast<const float4*>(x)[i];
        __half2* o = reinterpret_cast<__half2*>(xh) + (size_t)i * 2;
        o[0] = __floats2half2_rn(v.x, v.y);
        o[1] = __floats2half2_rn(v.z, v.w);
    }
}

// ---------------- L1: hist role + pack role ----------------

__global__ __launch_bounds__(256) void k_hist_pack(
    const int* __restrict__ dst, int E, int NBIN, int NBLK,
    int* __restrict__ hist_bm,
    const float* __restrict__ x, __half* __restrict__ xh, int n4, int pOff)
{
    __shared__ int cnt[MAXBIN];
    const int tid = threadIdx.x;

    if ((int)blockIdx.x >= NBLK) {            // pack role
        pack_body(x, xh, n4, (pOff + (int)blockIdx.x - NBLK) * 256 + tid);
        return;
    }

    const int blk = blockIdx.x;               // hist role
    for (int b = tid; b < NBIN; b += 256) cnt[b] = 0;
    __syncthreads();

    const int e0 = blk * CH;
    #pragma unroll
    for (int k = 0; k < CH / 1024; ++k) {
        const int g = (e0 >> 2) + k * 256 + tid;   // int4 index
        const int e = g << 2;
        if (e >= E) continue;
        if (e + 4 <= E) {
            const int4 d4 = reinterpret_cast<const int4*>(dst)[g];
            atomicAdd(&cnt[d4.x >> BSHIFT], 1);
            atomicAdd(&cnt[d4.y >> BSHIFT], 1);
            atomicAdd(&cnt[d4.z >> BSHIFT], 1);
            atomicAdd(&cnt[d4.w >> BSHIFT], 1);
        } else {
            for (int ee = e; ee < E; ++ee) atomicAdd(&cnt[dst[ee] >> BSHIFT], 1);
        }
    }
    __syncthreads();
    int* hb = hist_bm + (size_t)blk * NBIN;   // block-major, coalesced writes
    for (int b = tid; b < NBIN; b += 256) hb[b] = cnt[b];
}

// ---------------- L2: scan role + pack role ----------------
// Scan role: block handles TBINS consecutive bins; LDS-tiled transposed load,
// 256-thread Hillis-Steele; writes per-(bin,blk) local-exclusive 'partial' and
// the block's total into blocksum[blockIdx] (raw, NOT scanned).

__global__ __launch_bounds__(256) void k_pscan_pack(
    const int* __restrict__ hist_bm, int NBIN, int NBLK, int nb1,
    int* __restrict__ partial, int* __restrict__ blocksum,
    const float* __restrict__ x, __half* __restrict__ xh, int n4, int pOff)
{
    __shared__ int tile[TBINS][NBLKCAP + 1];
    __shared__ int sdata[256];
    const int t = threadIdx.x;

    if ((int)blockIdx.x >= nb1) {             // pack role
        pack_body(x, xh, n4, (pOff + (int)blockIdx.x - nb1) * 256 + t);
        return;
    }

    const int B0 = blockIdx.x * TBINS;        // scan role

    for (int g = t; g < TBINS * (NBLKCAP + 1); g += 256)
        (&tile[0][0])[g] = 0;
    __syncthreads();

    for (int g = t; g < NBLK * TBINS; g += 256) {
        const int blk = g >> 4;               // g / TBINS
        const int tb  = g & (TBINS - 1);
        const int bin = B0 + tb;
        if (bin < NBIN) tile[tb][blk] = hist_bm[(size_t)blk * NBIN + bin];
    }
    __syncthreads();

    const int tb  = t >> 4;
    const int bk0 = (t & 15) * 16;
    int v[16];
    int local = 0;
    #pragma unroll
    for (int k = 0; k < 16; ++k) { v[k] = tile[tb][bk0 + k]; local += v[k]; }

    sdata[t] = local;
    __syncthreads();
    #pragma unroll
    for (int off = 1; off < 256; off <<= 1) {
        int val = (t >= off) ? sdata[t - off] : 0;
        __syncthreads();
        sdata[t] += val;
        __syncthreads();
    }
    const int incl = sdata[t];
    int run = incl - local;
    if (t == 255) blocksum[blockIdx.x] = incl;   // raw total

    const int bin = B0 + tb;
    if (bin < NBIN) {
        #pragma unroll
        for (int k = 0; k < 16; ++k) {
            const int blk = bk0 + k;
            if (blk < NBLK) partial[(size_t)bin * NBLK + blk] = run;
            run += v[k];
        }
    }
}

// ---------------- L3: place role (+ in-LDS blocksum scan) + pack role ----------------

__global__ __launch_bounds__(256) void k_place_pack(
    const int* __restrict__ src, const int* __restrict__ dst, int E,
    int NBIN, int NBLK, int nb1,
    const int* __restrict__ partial, const int* __restrict__ blocksum,
    unsigned int* __restrict__ coarse,
    const float* __restrict__ x, __half* __restrict__ xh, int n4, int pOff)
{
    __shared__ int lcur[MAXBIN];
    __shared__ int sdata[256];
    __shared__ int sblk[256];
    const int tid = threadIdx.x;

    if ((int)blockIdx.x >= NBLK) {            // pack role
        pack_body(x, xh, n4, (pOff + (int)blockIdx.x - NBLK) * 256 + tid);
        return;
    }

    // exclusive scan of the (<=256) raw blocksum totals, once per block
    sdata[tid] = (tid < nb1) ? blocksum[tid] : 0;
    const int own = sdata[tid];
    __syncthreads();
    #pragma unroll
    for (int off = 1; off < 256; off <<= 1) {
        int val = (tid >= off) ? sdata[tid - off] : 0;
        __syncthreads();
        sdata[tid] += val;
        __syncthreads();
    }
    sblk[tid] = sdata[tid] - own;             // exclusive prefix
    __syncthreads();

    const int blk = blockIdx.x;               // place role
    for (int b = tid; b < NBIN; b += 256) {
        lcur[b] = partial[(size_t)b * NBLK + blk] + sblk[b / TBINS];
    }
    __syncthreads();

    const int e0 = blk * CH;
    #pragma unroll
    for (int k = 0; k < CH / 1024; ++k) {
        const int g = (e0 >> 2) + k * 256 + tid;
        const int e = g << 2;
        if (e >= E) continue;
        if (e + 4 <= E) {
            const int4 d4 = reinterpret_cast<const int4*>(dst)[g];
            const int4 s4 = reinterpret_cast<const int4*>(src)[g];
            int p;
            p = atomicAdd(&lcur[d4.x >> BSHIFT], 1);
            coarse[p] = (unsigned)s4.x | ((unsigned)(d4.x & (BWIDTH - 1)) << 17);
            p = atomicAdd(&lcur[d4.y >> BSHIFT], 1);
            coarse[p] = (unsigned)s4.y | ((unsigned)(d4.y & (BWIDTH - 1)) << 17);
            p = atomicAdd(&lcur[d4.z >> BSHIFT], 1);
            coarse[p] = (unsigned)s4.z | ((unsigned)(d4.z & (BWIDTH - 1)) << 17);
            p = atomicAdd(&lcur[d4.w >> BSHIFT], 1);
            coarse[p] = (unsigned)s4.w | ((unsigned)(d4.w & (BWIDTH - 1)) << 17);
        } else {
            for (int ee = e; ee < E; ++ee) {
                const int d = dst[ee], s = src[ee];
                int p = atomicAdd(&lcur[d >> BSHIFT], 1);
                coarse[p] = (unsigned)s | ((unsigned)(d & (BWIDTH - 1)) << 17);
            }
        }
    }
}

// ---------------- L4: per-bin LDS counting sort + fused accumulation ----------------
// 16 groups of 16 lanes; group gid owns nodes gid*2, gid*2+1. Lane sl owns
// channels sl*8..sl*8+7 (16B fp16 loads). 4-deep gather ladder; dst rows
// prefetched before the sort barriers. beg/end derived from raw blocksum via
// per-wave masked load + butterfly reduce (no scan2 kernel).

__global__ __launch_bounds__(256) void k_sort_accum(
    const __half* __restrict__ xh,
    const float* __restrict__ W2,
    const float* __restrict__ W3,
    const unsigned int* __restrict__ coarse,
    const int* __restrict__ partial, const int* __restrict__ blocksum,
    int NBIN, int NBLK, int nb1, int E, int N,
    float* __restrict__ out)
{
    __shared__ unsigned int raw[LDSCAP];
    __shared__ int srcl[LDSCAP];
    __shared__ int cnt[BWIDTH], offs[BWIDTH], cur[BWIDTH];

    const int bin  = blockIdx.x;
    const int tid  = threadIdx.x;
    const int lane = tid & 63;
    const int grp  = lane >> 4;
    const int sl   = lane & 15;
    const int gid  = (tid >> 6) * 4 + grp;
    const int choff = sl << 4;
    const char* xb = (const char*)xh;

    union H { int4 i4; __half2 h[4]; };

    // prefetch this group's two dst rows (latency hidden under the sort)
    const int node0 = (bin << BSHIFT) + gid * 2;
    const int node1 = node0 + 1;
    H uD0, uD1;
    uD0.i4 = make_int4(0, 0, 0, 0);
    uD1.i4 = make_int4(0, 0, 0, 0);
    if (node0 < N) uD0.i4 = *reinterpret_cast<const int4*>(xb + (((size_t)node0) << 8) + choff);
    if (node1 < N) uD1.i4 = *reinterpret_cast<const int4*>(xb + (((size_t)node1) << 8) + choff);

    // per-wave prefix of raw blocksum totals (j1 = bin/TBINS, j2 = (bin+1)/TBINS)
    const int j1 = bin / TBINS;
    const int j2 = (bin + 1) / TBINS;
    int s = 0;
    #pragma unroll
    for (int k = 0; k < 4; ++k) {
        const int idx = lane + k * 64;
        if (idx < j1) s += blocksum[idx];
    }
    #pragma unroll
    for (int off = 32; off > 0; off >>= 1) s += __shfl_xor(s, off, 64);
    const int pref1 = s;
    const int pref2 = pref1 + ((j2 > j1 && j2 <= nb1) ? blocksum[j1] : 0);

    const size_t i0 = (size_t)bin * NBLK;
    const int beg = partial[i0] + pref1;
    const int end = (bin + 1 < NBIN) ? partial[i0 + NBLK] + pref2 : E;
    const int mtot = end - beg;
    const int m = (mtot < LDSCAP) ? mtot : LDSCAP;

    if (tid < BWIDTH) cnt[tid] = 0;
    __syncthreads();

    for (int i = tid; i < m; i += 256) {
        unsigned u = coarse[beg + i];
        raw[i] = u;
        atomicAdd(&cnt[u >> 17], 1);
    }
    __syncthreads();

    if (tid < BWIDTH) {                       // lanes 0..31 of wave 0
        int c = cnt[tid];
        int v = c;
        #pragma unroll
        for (int d2 = 1; d2 < BWIDTH; d2 <<= 1) {
            int t2 = __shfl_up(v, d2, 64);
            if (tid >= d2) v += t2;
        }
        offs[tid] = v - c;
        cur[tid]  = v - c;
    }
    __syncthreads();

    for (int i = tid; i < m; i += 256) {
        const unsigned u = raw[i];
        const int p = atomicAdd(&cur[u >> 17], 1);
        srcl[p] = (int)(u & 0x1FFFFu);
    }
    __syncthreads();

    const float4 w3a = *reinterpret_cast<const float4*>(W3 + sl * 8);
    const float4 w3b = *reinterpret_cast<const float4*>(W3 + sl * 8 + 4);
    const float4 w2a = *reinterpret_cast<const float4*>(W2 + sl * 8);
    const float4 w2b = *reinterpret_cast<const float4*>(W2 + sl * 8 + 4);

    #pragma unroll
    for (int i = 0; i < 2; ++i) {
        const int node = (i == 0) ? node0 : node1;
        if (node >= N) continue;
        const int dl = gid * 2 + i;
        const H uD = (i == 0) ? uD0 : uD1;

        const float2 e0 = __half22float2(uD.h[0]);
        const float2 e1 = __half22float2(uD.h[1]);
        const float2 e2 = __half22float2(uD.h[2]);
        const float2 e3 = __half22float2(uD.h[3]);
        const float4 va = make_float4(w3a.x * e0.x, w3a.y * e0.y,
                                      w3a.z * e1.x, w3a.w * e1.y);
        const float4 vb = make_float4(w3b.x * e2.x, w3b.y * e2.y,
                                      w3b.z * e3.x, w3b.w * e3.y);

        float4 accA = make_float4(0.f, 0.f, 0.f, 0.f);
        float4 accB = make_float4(0.f, 0.f, 0.f, 0.f);

        const int b0 = offs[dl];
        const int c  = cnt[dl];

        int j = 0;
        for (; j + 4 <= c; j += 4) {          // 4 gathers in flight per group
            const int s0 = srcl[b0 + j];
            const int s1 = srcl[b0 + j + 1];
            const int s2 = srcl[b0 + j + 2];
            const int s3 = srcl[b0 + j + 3];
            H u0, u1, u2, u3;
            u0.i4 = *reinterpret_cast<const int4*>(xb + (((size_t)s0) << 8) + choff);
            u1.i4 = *reinterpret_cast<const int4*>(xb + (((size_t)s1) << 8) + choff);
            u2.i4 = *reinterpret_cast<const int4*>(xb + (((size_t)s2) << 8) + choff);
            u3.i4 = *reinterpret_cast<const int4*>(xb + (((size_t)s3) << 8) + choff);
            const float2 f00 = __half22float2(u0.h[0]);
            const float2 f01 = __half22float2(u0.h[1]);
            const float2 f02 = __half22float2(u0.h[2]);
            const float2 f03 = __half22float2(u0.h[3]);
            const float2 f10 = __half22float2(u1.h[0]);
            const float2 f11 = __half22float2(u1.h[1]);
            const float2 f12 = __half22float2(u1.h[2]);
            const float2 f13 = __half22float2(u1.h[3]);
            const float2 f20 = __half22float2(u2.h[0]);
            const float2 f21 = __half22float2(u2.h[1]);
            const float2 f22 = __half22float2(u2.h[2]);
            const float2 f23 = __half22float2(u2.h[3]);
            const float2 f30 = __half22float2(u3.h[0]);
            const float2 f31 = __half22float2(u3.h[1]);
            const float2 f32 = __half22float2(u3.h[2]);
            const float2 f33 = __half22float2(u3.h[3]);
            float p0 = f00.x * va.x + f00.y * va.y + f01.x * va.z + f01.y * va.w
                     + f02.x * vb.x + f02.y * vb.y + f03.x * vb.z + f03.y * vb.w;
            float p1 = f10.x * va.x + f10.y * va.y + f11.x * va.z + f11.y * va.w
                     + f12.x * vb.x + f12.y * vb.y + f13.x * vb.z + f13.y * vb.w;
            float p2 = f20.x * va.x + f20.y * va.y + f21.x * va.z + f21.y * va.w
                     + f22.x * vb.x + f22.y * vb.y + f23.x * vb.z + f23.y * vb.w;
            float p3 = f30.x * va.x + f30.y * va.y + f31.x * va.z + f31.y * va.w
                     + f32.x * vb.x + f32.y * vb.y + f33.x * vb.z + f33.y * vb.w;
            #pragma unroll
            for (int off = 1; off < 16; off <<= 1) {   // within-group reduce
                p0 += __shfl_xor(p0, off, 64);
                p1 += __shfl_xor(p1, off, 64);
                p2 += __shfl_xor(p2, off, 64);
                p3 += __shfl_xor(p3, off, 64);
            }
            accA.x += p0 * f00.x + p1 * f10.x + p2 * f20.x + p3 * f30.x;
            accA.y += p0 * f00.y + p1 * f10.y + p2 * f20.y + p3 * f30.y;
            accA.z += p0 * f01.x + p1 * f11.x + p2 * f21.x + p3 * f31.x;
            accA.w += p0 * f01.y + p1 * f11.y + p2 * f21.y + p3 * f31.y;
            accB.x += p0 * f02.x + p1 * f12.x + p2 * f22.x + p3 * f32.x;
            accB.y += p0 * f02.y + p1 * f12.y + p2 * f22.y + p3 * f32.y;
            accB.z += p0 * f03.x + p1 * f13.x + p2 * f23.x + p3 * f33.x;
            accB.w += p0 * f03.y + p1 * f13.y + p2 * f23.y + p3 * f33.y;
        }
        for (; j < c; ++j) {                  // remainder, whole group active
            H u0;
            u0.i4 = *reinterpret_cast<const int4*>(
                xb + (((size_t)srcl[b0 + j]) << 8) + choff);
            const float2 f0 = __half22float2(u0.h[0]);
            const float2 f1 = __half22float2(u0.h[1]);
            const float2 f2 = __half22float2(u0.h[2]);
            const float2 f3 = __half22float2(u0.h[3]);
            float p = f0.x * va.x + f0.y * va.y + f1.x * va.z + f1.y * va.w
                    + f2.x * vb.x + f2.y * vb.y + f3.x * vb.z + f3.y * vb.w;
            #pragma unroll
            for (int off = 1; off < 16; off <<= 1) p += __shfl_xor(p, off, 64);
            accA.x += p * f0.x; accA.y += p * f0.y;
            accA.z += p * f1.x; accA.w += p * f1.y;
            accB.x += p * f2.x; accB.y += p * f2.y;
            accB.z += p * f3.x; accB.w += p * f3.y;
        }
        // LDS-capacity overflow (normally zero iterations)
        for (int i2 = LDSCAP; i2 < mtot; ++i2) {
            const unsigned u = coarse[beg + i2];
            if ((int)(u >> 17) != dl) continue;
            H u0;
            u0.i4 = *reinterpret_cast<const int4*>(
                xb + (((size_t)(u & 0x1FFFFu)) << 8) + choff);
            const float2 f0 = __half22float2(u0.h[0]);
            const float2 f1 = __half22float2(u0.h[1]);
            const float2 f2 = __half22float2(u0.h[2]);
            const float2 f3 = __half22float2(u0.h[3]);
            float p = f0.x * va.x + f0.y * va.y + f1.x * va.z + f1.y * va.w
                    + f2.x * vb.x + f2.y * vb.y + f3.x * vb.z + f3.y * vb.w;
            #pragma unroll
            for (int off = 1; off < 16; off <<= 1) p += __shfl_xor(p, off, 64);
            accA.x += p * f0.x; accA.y += p * f0.y;
            accA.z += p * f1.x; accA.w += p * f1.y;
            accB.x += p * f2.x; accB.y += p * f2.y;
            accB.z += p * f3.x; accB.w += p * f3.y;
        }

        accA.x *= w2a.x; accA.y *= w2a.y; accA.z *= w2a.z; accA.w *= w2a.w;
        accB.x *= w2b.x; accB.y *= w2b.y; accB.z *= w2b.z; accB.w *= w2b.w;
        float* orow = out + (size_t)node * CCH + sl * 8;
        *reinterpret_cast<float4*>(orow)     = accA;
        *reinterpret_cast<float4*>(orow + 4) = accB;
    }
}

// ---------------- last-resort fallback: pure fp32 atomics (R1) ----------------

__global__ __launch_bounds__(256) void edge_gather_scatter(
    const float* __restrict__ x, const int* __restrict__ edge_index,
    const float* __restrict__ W2, const float* __restrict__ W3,
    float* __restrict__ out, int E)
{
    const int e    = (blockIdx.x * blockDim.x + threadIdx.x) >> 6;
    const int lane = threadIdx.x & 63;
    if (e >= E) return;
    const int s = edge_index[e];
    const int d = edge_index[E + e];
    const float2 xs = *reinterpret_cast<const float2*>(x + (size_t)s * CCH + lane * 2);
    const float2 xd = *reinterpret_cast<const float2*>(x + (size_t)d * CCH + lane * 2);
    const float2 w3 = *reinterpret_cast<const float2*>(W3 + lane * 2);
    const float2 w2 = *reinterpret_cast<const float2*>(W2 + lane * 2);
    float p = xs.x * w3.x * xd.x + xs.y * w3.y * xd.y;
    #pragma unroll
    for (int off = 32; off > 0; off >>= 1) p += __shfl_xor(p, off, 64);
    float* o = out + (size_t)d * CCH + lane * 2;
    atomicAdd(o,     p * xs.x * w2.x);
    atomicAdd(o + 1, p * xs.y * w2.y);
}

// ---------------- launch ----------------

extern "C" void kernel_launch(void* const* d_in, const int* in_sizes, int n_in,
                              void* d_out, int out_size, void* d_ws, size_t ws_size,
                              hipStream_t stream) {
    const float* x          = (const float*)d_in[0];
    const int*   edge_index = (const int*)  d_in[1];
    const float* W2         = (const float*)d_in[2];
    const float* W3         = (const float*)d_in[3];
    float*       out        = (float*)d_out;

    const int E = in_sizes[1] / 2;
    const int N = out_size / CCH;
    const int* src = edge_index;
    const int* dst = edge_index + E;

    const int NBIN = (N + BWIDTH - 1) >> BSHIFT;
    const int NBLK = (E + CH - 1) / CH;
    const long long Mll = (long long)NBIN * NBLK;
    const int M = (int)Mll;
    const int nb1 = (NBIN + TBINS - 1) / TBINS;

    const size_t xh_bytes = (size_t)N * CCH * 2;
    const size_t need = xh_bytes + (size_t)E * 4 + 2 * (size_t)M * 4 + 1024 * 4;

    const bool aligned16 = (((uintptr_t)src & 15) == 0) && (((uintptr_t)dst & 15) == 0);

    if (N <= (1 << 17) && NBIN <= MAXBIN && NBLK <= NBLKCAP && Mll <= (1LL << 20) &&
        nb1 <= 256 && aligned16 && ws_size >= need) {
        char* base = (char*)d_ws;
        __half* xh       = (__half*)base;        base += xh_bytes;
        unsigned* coarse = (unsigned*)base;      base += (size_t)E * 4;
        int* hist_bm     = (int*)base;           base += (size_t)M * 4;
        int* partial     = (int*)base;           base += (size_t)M * 4;
        int* blocksum    = (int*)base;

        const int n4 = N * CCH / 4;
        const int nPack = (n4 + 255) / 256;
        const int nP1 = (nPack + 2) / 3;
        const int nP2 = (nPack + 2) / 3;
        const int nP3 = nPack - nP1 - nP2;

        k_hist_pack<<<NBLK + nP1, 256, 0, stream>>>(dst, E, NBIN, NBLK, hist_bm,
                                                    x, xh, n4, 0);
        k_pscan_pack<<<nb1 + nP2, 256, 0, stream>>>(hist_bm, NBIN, NBLK, nb1,
                                                    partial, blocksum,
                                                    x, xh, n4, nP1);
        k_place_pack<<<NBLK + nP3, 256, 0, stream>>>(src, dst, E, NBIN, NBLK, nb1,
                                                     partial, blocksum, coarse,
                                                     x, xh, n4, nP1 + nP2);
        k_sort_accum<<<NBIN, 256, 0, stream>>>(xh, W2, W3, coarse,
                                               partial, blocksum,
                                               NBIN, NBLK, nb1, E, N, out);
        return;
    }

    // last resort: pure atomics
    hipMemsetAsync(d_out, 0, (size_t)out_size * sizeof(float), stream);
    const int grid = (E * 64 + 255) / 256;
    edge_gather_scatter<<<grid, 256, 0, stream>>>(x, edge_index, W2, W3, out, E);
}

// Round 13
// 119.390 us; speedup vs baseline: 1.1667x; 1.0384x over previous
//
#include <hip/hip_runtime.h>
#include <hip/hip_fp16.h>

// out[n,c] = sum_{e: dst[e]==n} ( sum_k x[src[e],k]*W3[k]*x[dst[e],k] ) * x[src[e],c] * W2[c]
// B=1, N=100000, E=1600000, C=128.
//
// Pipeline (4 launches; fp16 pack spread as a co-role across the first three):
//   k_hist_pack : hist-role blocks (coarse-bin histogram, bin=dst>>5) + pack
//   k_pscan_pack: scan-role blocks (LDS-tiled transpose scan; blocksum = raw
//                 per-scanblock totals) + pack
//   k_place_pack: place-role blocks (deterministic placement of (dstlow|src);
//                 blocksum prefix folded in via in-LDS scan) + pack
//   k_sort_accum: per-bin LDS counting sort + fused accumulation.
//                 R13: v_dot2_f32_f16 (fdot2) for the 8-ch dot (fp32 acc) and
//                 fp16 hfma2 accumulation -> ~2x fewer VALU ops per edge.
// Fallback: R1-style pure-atomic kernel if constraints unmet.

#define CCH 128
#define BSHIFT 5
#define BWIDTH 32              // nodes per bin
#define MAXBIN 4096            // supports N <= 131072 (17-bit src pack)
#define CH 8192                // edges per partition block
#define LDSCAP 1280            // max edges staged per bin (mean ~512)
#define TBINS 16               // bins per pscan block
#define NBLKCAP 256            // max partition blocks supported by pscan tile

typedef _Float16 half2_t __attribute__((ext_vector_type(2)));

__device__ __forceinline__ float dot8_f16(const __half2* q, const half2_t* v) {
#if __has_builtin(__builtin_amdgcn_fdot2)
    const half2_t* qv = reinterpret_cast<const half2_t*>(q);
    float p = __builtin_amdgcn_fdot2(qv[0], v[0], 0.f, false);
    p = __builtin_amdgcn_fdot2(qv[1], v[1], p, false);
    p = __builtin_amdgcn_fdot2(qv[2], v[2], p, false);
    p = __builtin_amdgcn_fdot2(qv[3], v[3], p, false);
    return p;
#else
    const __half2* vv = reinterpret_cast<const __half2*>(v);
    __half2 t = __hmul2(q[0], vv[0]);
    t = __hfma2(q[1], vv[1], t);
    t = __hfma2(q[2], vv[2], t);
    t = __hfma2(q[3], vv[3], t);
    float2 tf = __half22float2(t);
    return tf.x + tf.y;
#endif
}

// ---------------- pack helper (device inline) ----------------

__device__ __forceinline__ void pack_body(const float* __restrict__ x,
                                          __half* __restrict__ xh,
                                          int n4, int i) {
    if (i < n4) {
        float4 v = reinterpret_cast<const float4*>(x)[i];
        __half2* o = reinterpret_cast<__half2*>(xh) + (size_t)i * 2;
        o[0] = __floats2half2_rn(v.x, v.y);
        o[1] = __floats2half2_rn(v.z, v.w);
    }
}

// ---------------- L1: hist role + pack role ----------------

__global__ __launch_bounds__(256) void k_hist_pack(
    const int* __restrict__ dst, int E, int NBIN, int NBLK,
    int* __restrict__ hist_bm,
    const float* __restrict__ x, __half* __restrict__ xh, int n4, int pOff)
{
    __shared__ int cnt[MAXBIN];
    const int tid = threadIdx.x;

    if ((int)blockIdx.x >= NBLK) {            // pack role
        pack_body(x, xh, n4, (pOff + (int)blockIdx.x - NBLK) * 256 + tid);
        return;
    }

    const int blk = blockIdx.x;               // hist role
    for (int b = tid; b < NBIN; b += 256) cnt[b] = 0;
    __syncthreads();

    const int e0 = blk * CH;
    #pragma unroll
    for (int k = 0; k < CH / 1024; ++k) {
        const int g = (e0 >> 2) + k * 256 + tid;   // int4 index
        const int e = g << 2;
        if (e >= E) continue;
        if (e + 4 <= E) {
            const int4 d4 = reinterpret_cast<const int4*>(dst)[g];
            atomicAdd(&cnt[d4.x >> BSHIFT], 1);
            atomicAdd(&cnt[d4.y >> BSHIFT], 1);
            atomicAdd(&cnt[d4.z >> BSHIFT], 1);
            atomicAdd(&cnt[d4.w >> BSHIFT], 1);
        } else {
            for (int ee = e; ee < E; ++ee) atomicAdd(&cnt[dst[ee] >> BSHIFT], 1);
        }
    }
    __syncthreads();
    int* hb = hist_bm + (size_t)blk * NBIN;   // block-major, coalesced writes
    for (int b = tid; b < NBIN; b += 256) hb[b] = cnt[b];
}

// ---------------- L2: scan role + pack role ----------------

__global__ __launch_bounds__(256) void k_pscan_pack(
    const int* __restrict__ hist_bm, int NBIN, int NBLK, int nb1,
    int* __restrict__ partial, int* __restrict__ blocksum,
    const float* __restrict__ x, __half* __restrict__ xh, int n4, int pOff)
{
    __shared__ int tile[TBINS][NBLKCAP + 1];
    __shared__ int sdata[256];
    const int t = threadIdx.x;

    if ((int)blockIdx.x >= nb1) {             // pack role
        pack_body(x, xh, n4, (pOff + (int)blockIdx.x - nb1) * 256 + t);
        return;
    }

    const int B0 = blockIdx.x * TBINS;        // scan role

    for (int g = t; g < TBINS * (NBLKCAP + 1); g += 256)
        (&tile[0][0])[g] = 0;
    __syncthreads();

    for (int g = t; g < NBLK * TBINS; g += 256) {
        const int blk = g >> 4;               // g / TBINS
        const int tb  = g & (TBINS - 1);
        const int bin = B0 + tb;
        if (bin < NBIN) tile[tb][blk] = hist_bm[(size_t)blk * NBIN + bin];
    }
    __syncthreads();

    const int tb  = t >> 4;
    const int bk0 = (t & 15) * 16;
    int v[16];
    int local = 0;
    #pragma unroll
    for (int k = 0; k < 16; ++k) { v[k] = tile[tb][bk0 + k]; local += v[k]; }

    sdata[t] = local;
    __syncthreads();
    #pragma unroll
    for (int off = 1; off < 256; off <<= 1) {
        int val = (t >= off) ? sdata[t - off] : 0;
        __syncthreads();
        sdata[t] += val;
        __syncthreads();
    }
    const int incl = sdata[t];
    int run = incl - local;
    if (t == 255) blocksum[blockIdx.x] = incl;   // raw total

    const int bin = B0 + tb;
    if (bin < NBIN) {
        #pragma unroll
        for (int k = 0; k < 16; ++k) {
            const int blk = bk0 + k;
            if (blk < NBLK) partial[(size_t)bin * NBLK + blk] = run;
            run += v[k];
        }
    }
}

// ---------------- L3: place role (+ in-LDS blocksum scan) + pack role ----------------

__global__ __launch_bounds__(256) void k_place_pack(
    const int* __restrict__ src, const int* __restrict__ dst, int E,
    int NBIN, int NBLK, int nb1,
    const int* __restrict__ partial, const int* __restrict__ blocksum,
    unsigned int* __restrict__ coarse,
    const float* __restrict__ x, __half* __restrict__ xh, int n4, int pOff)
{
    __shared__ int lcur[MAXBIN];
    __shared__ int sdata[256];
    __shared__ int sblk[256];
    const int tid = threadIdx.x;

    if ((int)blockIdx.x >= NBLK) {            // pack role
        pack_body(x, xh, n4, (pOff + (int)blockIdx.x - NBLK) * 256 + tid);
        return;
    }

    // exclusive scan of the (<=256) raw blocksum totals, once per block
    sdata[tid] = (tid < nb1) ? blocksum[tid] : 0;
    const int own = sdata[tid];
    __syncthreads();
    #pragma unroll
    for (int off = 1; off < 256; off <<= 1) {
        int val = (tid >= off) ? sdata[tid - off] : 0;
        __syncthreads();
        sdata[tid] += val;
        __syncthreads();
    }
    sblk[tid] = sdata[tid] - own;             // exclusive prefix
    __syncthreads();

    const int blk = blockIdx.x;               // place role
    for (int b = tid; b < NBIN; b += 256) {
        lcur[b] = partial[(size_t)b * NBLK + blk] + sblk[b / TBINS];
    }
    __syncthreads();

    const int e0 = blk * CH;
    #pragma unroll
    for (int k = 0; k < CH / 1024; ++k) {
        const int g = (e0 >> 2) + k * 256 + tid;
        const int e = g << 2;
        if (e >= E) continue;
        if (e + 4 <= E) {
            const int4 d4 = reinterpret_cast<const int4*>(dst)[g];
            const int4 s4 = reinterpret_cast<const int4*>(src)[g];
            int p;
            p = atomicAdd(&lcur[d4.x >> BSHIFT], 1);
            coarse[p] = (unsigned)s4.x | ((unsigned)(d4.x & (BWIDTH - 1)) << 17);
            p = atomicAdd(&lcur[d4.y >> BSHIFT], 1);
            coarse[p] = (unsigned)s4.y | ((unsigned)(d4.y & (BWIDTH - 1)) << 17);
            p = atomicAdd(&lcur[d4.z >> BSHIFT], 1);
            coarse[p] = (unsigned)s4.z | ((unsigned)(d4.z & (BWIDTH - 1)) << 17);
            p = atomicAdd(&lcur[d4.w >> BSHIFT], 1);
            coarse[p] = (unsigned)s4.w | ((unsigned)(d4.w & (BWIDTH - 1)) << 17);
        } else {
            for (int ee = e; ee < E; ++ee) {
                const int d = dst[ee], s = src[ee];
                int p = atomicAdd(&lcur[d >> BSHIFT], 1);
                coarse[p] = (unsigned)s | ((unsigned)(d & (BWIDTH - 1)) << 17);
            }
        }
    }
}

// ---------------- L4: per-bin LDS counting sort + fused accumulation ----------------
// 16 groups of 16 lanes; group gid owns nodes gid*2, gid*2+1. Lane sl owns
// channels sl*8..sl*8+7 (16B fp16 loads). 4-deep gather ladder; dst rows
// prefetched before the sort barriers; fdot2 dot + fp16 hfma2 accumulation.

__global__ __launch_bounds__(256) void k_sort_accum(
    const __half* __restrict__ xh,
    const float* __restrict__ W2,
    const float* __restrict__ W3,
    const unsigned int* __restrict__ coarse,
    const int* __restrict__ partial, const int* __restrict__ blocksum,
    int NBIN, int NBLK, int nb1, int E, int N,
    float* __restrict__ out)
{
    __shared__ unsigned int raw[LDSCAP];
    __shared__ int srcl[LDSCAP];
    __shared__ int cnt[BWIDTH], offs[BWIDTH], cur[BWIDTH];

    const int bin  = blockIdx.x;
    const int tid  = threadIdx.x;
    const int lane = tid & 63;
    const int grp  = lane >> 4;
    const int sl   = lane & 15;
    const int gid  = (tid >> 6) * 4 + grp;
    const int choff = sl << 4;
    const char* xb = (const char*)xh;

    union H { int4 i4; __half2 h[4]; };

    // prefetch this group's two dst rows (latency hidden under the sort)
    const int node0 = (bin << BSHIFT) + gid * 2;
    const int node1 = node0 + 1;
    H uD0, uD1;
    uD0.i4 = make_int4(0, 0, 0, 0);
    uD1.i4 = make_int4(0, 0, 0, 0);
    if (node0 < N) uD0.i4 = *reinterpret_cast<const int4*>(xb + (((size_t)node0) << 8) + choff);
    if (node1 < N) uD1.i4 = *reinterpret_cast<const int4*>(xb + (((size_t)node1) << 8) + choff);

    // per-wave prefix of raw blocksum totals
    const int j1 = bin / TBINS;
    const int j2 = (bin + 1) / TBINS;
    int s = 0;
    #pragma unroll
    for (int k = 0; k < 4; ++k) {
        const int idx = lane + k * 64;
        if (idx < j1) s += blocksum[idx];
    }
    #pragma unroll
    for (int off = 32; off > 0; off >>= 1) s += __shfl_xor(s, off, 64);
    const int pref1 = s;
    const int pref2 = pref1 + ((j2 > j1 && j2 <= nb1) ? blocksum[j1] : 0);

    const size_t i0 = (size_t)bin * NBLK;
    const int beg = partial[i0] + pref1;
    const int end = (bin + 1 < NBIN) ? partial[i0 + NBLK] + pref2 : E;
    const int mtot = end - beg;
    const int m = (mtot < LDSCAP) ? mtot : LDSCAP;

    if (tid < BWIDTH) cnt[tid] = 0;
    __syncthreads();

    for (int i = tid; i < m; i += 256) {
        unsigned u = coarse[beg + i];
        raw[i] = u;
        atomicAdd(&cnt[u >> 17], 1);
    }
    __syncthreads();

    if (tid < BWIDTH) {                       // lanes 0..31 of wave 0
        int c = cnt[tid];
        int v = c;
        #pragma unroll
        for (int d2 = 1; d2 < BWIDTH; d2 <<= 1) {
            int t2 = __shfl_up(v, d2, 64);
            if (tid >= d2) v += t2;
        }
        offs[tid] = v - c;
        cur[tid]  = v - c;
    }
    __syncthreads();

    for (int i = tid; i < m; i += 256) {
        const unsigned u = raw[i];
        const int p = atomicAdd(&cur[u >> 17], 1);
        srcl[p] = (int)(u & 0x1FFFFu);
    }
    __syncthreads();

    const float4 w3a = *reinterpret_cast<const float4*>(W3 + sl * 8);
    const float4 w3b = *reinterpret_cast<const float4*>(W3 + sl * 8 + 4);
    const float4 w2a = *reinterpret_cast<const float4*>(W2 + sl * 8);
    const float4 w2b = *reinterpret_cast<const float4*>(W2 + sl * 8 + 4);

    #pragma unroll
    for (int i = 0; i < 2; ++i) {
        const int node = (i == 0) ? node0 : node1;
        if (node >= N) continue;
        const int dl = gid * 2 + i;
        const H uD = (i == 0) ? uD0 : uD1;

        // v = W3 .* x[node] for this lane's 8 channels, as 4 half2
        const float2 e0 = __half22float2(uD.h[0]);
        const float2 e1 = __half22float2(uD.h[1]);
        const float2 e2 = __half22float2(uD.h[2]);
        const float2 e3 = __half22float2(uD.h[3]);
        half2_t vh[4];
        {
            __half2 t0 = __floats2half2_rn(w3a.x * e0.x, w3a.y * e0.y);
            __half2 t1 = __floats2half2_rn(w3a.z * e1.x, w3a.w * e1.y);
            __half2 t2 = __floats2half2_rn(w3b.x * e2.x, w3b.y * e2.y);
            __half2 t3 = __floats2half2_rn(w3b.z * e3.x, w3b.w * e3.y);
            vh[0] = *reinterpret_cast<half2_t*>(&t0);
            vh[1] = *reinterpret_cast<half2_t*>(&t1);
            vh[2] = *reinterpret_cast<half2_t*>(&t2);
            vh[3] = *reinterpret_cast<half2_t*>(&t3);
        }

        __half2 acc[4];
        acc[0] = __floats2half2_rn(0.f, 0.f);
        acc[1] = acc[0]; acc[2] = acc[0]; acc[3] = acc[0];

        const int b0 = offs[dl];
        const int c  = cnt[dl];

        int j = 0;
        for (; j + 4 <= c; j += 4) {          // 4 gathers in flight per group
            const int s0 = srcl[b0 + j];
            const int s1 = srcl[b0 + j + 1];
            const int s2 = srcl[b0 + j + 2];
            const int s3 = srcl[b0 + j + 3];
            H u0, u1, u2, u3;
            u0.i4 = *reinterpret_cast<const int4*>(xb + (((size_t)s0) << 8) + choff);
            u1.i4 = *reinterpret_cast<const int4*>(xb + (((size_t)s1) << 8) + choff);
            u2.i4 = *reinterpret_cast<const int4*>(xb + (((size_t)s2) << 8) + choff);
            u3.i4 = *reinterpret_cast<const int4*>(xb + (((size_t)s3) << 8) + choff);
            float p0 = dot8_f16(u0.h, vh);
            float p1 = dot8_f16(u1.h, vh);
            float p2 = dot8_f16(u2.h, vh);
            float p3 = dot8_f16(u3.h, vh);
            #pragma unroll
            for (int off = 1; off < 16; off <<= 1) {   // within-group reduce
                p0 += __shfl_xor(p0, off, 64);
                p1 += __shfl_xor(p1, off, 64);
                p2 += __shfl_xor(p2, off, 64);
                p3 += __shfl_xor(p3, off, 64);
            }
            const __half2 ph0 = __half2half2(__float2half(p0));
            const __half2 ph1 = __half2half2(__float2half(p1));
            const __half2 ph2 = __half2half2(__float2half(p2));
            const __half2 ph3 = __half2half2(__float2half(p3));
            #pragma unroll
            for (int q = 0; q < 4; ++q) {
                acc[q] = __hfma2(ph0, u0.h[q], acc[q]);
                acc[q] = __hfma2(ph1, u1.h[q], acc[q]);
                acc[q] = __hfma2(ph2, u2.h[q], acc[q]);
                acc[q] = __hfma2(ph3, u3.h[q], acc[q]);
            }
        }
        for (; j < c; ++j) {                  // remainder, whole group active
            H u0;
            u0.i4 = *reinterpret_cast<const int4*>(
                xb + (((size_t)srcl[b0 + j]) << 8) + choff);
            float p = dot8_f16(u0.h, vh);
            #pragma unroll
            for (int off = 1; off < 16; off <<= 1) p += __shfl_xor(p, off, 64);
            const __half2 ph = __half2half2(__float2half(p));
            #pragma unroll
            for (int q = 0; q < 4; ++q) acc[q] = __hfma2(ph, u0.h[q], acc[q]);
        }
        // LDS-capacity overflow (normally zero iterations)
        for (int i2 = LDSCAP; i2 < mtot; ++i2) {
            const unsigned u = coarse[beg + i2];
            if ((int)(u >> 17) != dl) continue;
            H u0;
            u0.i4 = *reinterpret_cast<const int4*>(
                xb + (((size_t)(u & 0x1FFFFu)) << 8) + choff);
            float p = dot8_f16(u0.h, vh);
            #pragma unroll
            for (int off = 1; off < 16; off <<= 1) p += __shfl_xor(p, off, 64);
            const __half2 ph = __half2half2(__float2half(p));
            #pragma unroll
            for (int q = 0; q < 4; ++q) acc[q] = __hfma2(ph, u0.h[q], acc[q]);
        }

        const float2 a0 = __half22float2(acc[0]);
        const float2 a1 = __half22float2(acc[1]);
        const float2 a2 = __half22float2(acc[2]);
        const float2 a3 = __half22float2(acc[3]);
        float4 oA = make_float4(a0.x * w2a.x, a0.y * w2a.y, a1.x * w2a.z, a1.y * w2a.w);
        float4 oB = make_float4(a2.x * w2b.x, a2.y * w2b.y, a3.x * w2b.z, a3.y * w2b.w);
        float* orow = out + (size_t)node * CCH + sl * 8;
        *reinterpret_cast<float4*>(orow)     = oA;
        *reinterpret_cast<float4*>(orow + 4) = oB;
    }
}

// ---------------- last-resort fallback: pure fp32 atomics (R1) ----------------

__global__ __launch_bounds__(256) void edge_gather_scatter(
    const float* __restrict__ x, const int* __restrict__ edge_index,
    const float* __restrict__ W2, const float* __restrict__ W3,
    float* __restrict__ out, int E)
{
    const int e    = (blockIdx.x * blockDim.x + threadIdx.x) >> 6;
    const int lane = threadIdx.x & 63;
    if (e >= E) return;
    const int s = edge_index[e];
    const int d = edge_index[E + e];
    const float2 xs = *reinterpret_cast<const float2*>(x + (size_t)s * CCH + lane * 2);
    const float2 xd = *reinterpret_cast<const float2*>(x + (size_t)d * CCH + lane * 2);
    const float2 w3 = *reinterpret_cast<const float2*>(W3 + lane * 2);
    const float2 w2 = *reinterpret_cast<const float2*>(W2 + lane * 2);
    float p = xs.x * w3.x * xd.x + xs.y * w3.y * xd.y;
    #pragma unroll
    for (int off = 32; off > 0; off >>= 1) p += __shfl_xor(p, off, 64);
    float* o = out + (size_t)d * CCH + lane * 2;
    atomicAdd(o,     p * xs.x * w2.x);
    atomicAdd(o + 1, p * xs.y * w2.y);
}

// ---------------- launch ----------------

extern "C" void kernel_launch(void* const* d_in, const int* in_sizes, int n_in,
                              void* d_out, int out_size, void* d_ws, size_t ws_size,
                              hipStream_t stream) {
    const float* x          = (const float*)d_in[0];
    const int*   edge_index = (const int*)  d_in[1];
    const float* W2         = (const float*)d_in[2];
    const float* W3         = (const float*)d_in[3];
    float*       out        = (float*)d_out;

    const int E = in_sizes[1] / 2;
    const int N = out_size / CCH;
    const int* src = edge_index;
    const int* dst = edge_index + E;

    const int NBIN = (N + BWIDTH - 1) >> BSHIFT;
    const int NBLK = (E + CH - 1) / CH;
    const long long Mll = (long long)NBIN * NBLK;
    const int M = (int)Mll;
    const int nb1 = (NBIN + TBINS - 1) / TBINS;

    const size_t xh_bytes = (size_t)N * CCH * 2;
    const size_t need = xh_bytes + (size_t)E * 4 + 2 * (size_t)M * 4 + 1024 * 4;

    const bool aligned16 = (((uintptr_t)src & 15) == 0) && (((uintptr_t)dst & 15) == 0);

    if (N <= (1 << 17) && NBIN <= MAXBIN && NBLK <= NBLKCAP && Mll <= (1LL << 20) &&
        nb1 <= 256 && aligned16 && ws_size >= need) {
        char* base = (char*)d_ws;
        __half* xh       = (__half*)base;        base += xh_bytes;
        unsigned* coarse = (unsigned*)base;      base += (size_t)E * 4;
        int* hist_bm     = (int*)base;           base += (size_t)M * 4;
        int* partial     = (int*)base;           base += (size_t)M * 4;
        int* blocksum    = (int*)base;

        const int n4 = N * CCH / 4;
        const int nPack = (n4 + 255) / 256;
        const int nP1 = (nPack * 35) / 100;
        const int nP2 = (nPack * 40) / 100;
        const int nP3 = nPack - nP1 - nP2;

        k_hist_pack<<<NBLK + nP1, 256, 0, stream>>>(dst, E, NBIN, NBLK, hist_bm,
                                                    x, xh, n4, 0);
        k_pscan_pack<<<nb1 + nP2, 256, 0, stream>>>(hist_bm, NBIN, NBLK, nb1,
                                                    partial, blocksum,
                                                    x, xh, n4, nP1);
        k_place_pack<<<NBLK + nP3, 256, 0, stream>>>(src, dst, E, NBIN, NBLK, nb1,
                                                     partial, blocksum, coarse,
                                                     x, xh, n4, nP1 + nP2);
        k_sort_accum<<<NBIN, 256, 0, stream>>>(xh, W2, W3, coarse,
                                               partial, blocksum,
                                               NBIN, NBLK, nb1, E, N, out);
        return;
    }

    // last resort: pure atomics
    hipMemsetAsync(d_out, 0, (size_t)out_size * sizeof(float), stream);
    const int grid = (E * 64 + 255) / 256;
    edge_gather_scatter<<<grid, 256, 0, stream>>>(x, edge_index, W2, W3, out, E);
}